// Round 3
// baseline (389.319 us; speedup 1.0000x reference)
//
#include <hip/hip_runtime.h>
#include <hip/hip_bf16.h>
#include <math.h>

#define NBINS 15
#define NB1 2048          // stage-1 blocks
#define BLK 256           // threads per block (4 waves)

// Stage 1: one wave per row, register-double-buffered across rows so the next
// row's 4KB is always in flight while the current row is reduced.
// Wave reduction: (sum) + packed u64 (sortable-max | ~argmax) butterfly.
__global__ __launch_bounds__(BLK, 4) void ece_rows_kernel(
    const float* __restrict__ logits,
    const int*   __restrict__ labels,
    float* __restrict__ partials,   // [3*NBINS][NB1] transposed
    int N, int C)
{
    __shared__ float sb[3 * NBINS];
    const int t = threadIdx.x;
    if (t < 3 * NBINS) sb[t] = 0.0f;
    __syncthreads();

    const int lane   = t & 63;
    const int wave   = (blockIdx.x * BLK + t) >> 6;
    const int nwaves = (NB1 * BLK) >> 6;
    const int nvec   = (C + 3) >> 2;            // 250 for C=1000

    const int  i0 = lane, i1 = lane + 64, i2 = lane + 128, i3 = lane + 192;
    const bool q0 = i0 < nvec, q1 = i1 < nvec, q2 = i2 < nvec, q3 = i3 < nvec;
    const float4 NEG = make_float4(-INFINITY, -INFINITY, -INFINITY, -INFINITY);

    float4 v0 = NEG, v1 = NEG, v2 = NEG, v3 = NEG;
    int lab = 0;
    int row = wave;
    if (row < N) {
        const float4* __restrict__ rp = (const float4*)(logits + (size_t)row * C);
        v0 = q0 ? rp[i0] : NEG;
        v1 = q1 ? rp[i1] : NEG;
        v2 = q2 ? rp[i2] : NEG;
        v3 = q3 ? rp[i3] : NEG;
        lab = labels[row];
    }

    while (row < N) {
        // ---- prefetch next row (loads issue before current row's waitcnt) ----
        const int nrow = row + nwaves;
        float4 w0 = NEG, w1 = NEG, w2 = NEG, w3 = NEG;
        int nlab = 0;
        if (nrow < N) {
            const float4* __restrict__ rp = (const float4*)(logits + (size_t)nrow * C);
            w0 = q0 ? rp[i0] : NEG;
            w1 = q1 ? rp[i1] : NEG;
            w2 = q2 ? rp[i2] : NEG;
            w3 = q3 ? rp[i3] : NEG;
            nlab = labels[nrow];
        }

        // ---- process current row ----
        const float* e0 = (const float*)&v0;
        const float* e1 = (const float*)&v1;
        const float* e2 = (const float*)&v2;
        const float* e3 = (const float*)&v3;

        // sum of exp (4 independent accumulators); exp(-inf)=0 covers the tail
        float s0 = __expf(e0[0]) + __expf(e0[1]) + __expf(e0[2]) + __expf(e0[3]);
        float s1 = __expf(e1[0]) + __expf(e1[1]) + __expf(e1[2]) + __expf(e1[3]);
        float s2 = __expf(e2[0]) + __expf(e2[1]) + __expf(e2[2]) + __expf(e2[3]);
        float s3 = __expf(e3[0]) + __expf(e3[1]) + __expf(e3[2]) + __expf(e3[3]);
        float s  = (s0 + s1) + (s2 + s3);

        // max via tree
        float m0 = fmaxf(fmaxf(e0[0], e0[1]), fmaxf(e0[2], e0[3]));
        float m1 = fmaxf(fmaxf(e1[0], e1[1]), fmaxf(e1[2], e1[3]));
        float m2 = fmaxf(fmaxf(e2[0], e2[1]), fmaxf(e2[2], e2[3]));
        float m3 = fmaxf(fmaxf(e3[0], e3[1]), fmaxf(e3[2], e3[3]));
        float m  = fmaxf(fmaxf(m0, m1), fmaxf(m2, m3));

        // argmax = smallest col with e==m: overwrite scanning cols DESCENDING
        int am = 0x7FFFFFFF;
        {
            const float* es[4] = { e0, e1, e2, e3 };
            #pragma unroll
            for (int k = 3; k >= 0; --k) {
                const int base = (lane + 64 * k) * 4;
                #pragma unroll
                for (int j = 3; j >= 0; --j)
                    am = (es[k][j] == m) ? (base + j) : am;
            }
        }

        // pack (sortable float, inverted index) -> u64; max-key == (max val, min col)
        unsigned int mb = __float_as_uint(m);
        unsigned int ms = mb ^ ((unsigned int)((int)mb >> 31) | 0x80000000u);
        unsigned long long key =
            ((unsigned long long)ms << 32) | (unsigned int)(0x7FFFFFFF - am);

        #pragma unroll
        for (int off = 32; off; off >>= 1) {
            unsigned long long k2 = __shfl_xor(key, off, 64);
            float sv              = __shfl_xor(s,   off, 64);
            s += sv;
            key = (k2 > key) ? k2 : key;
        }

        if (lane == 0) {
            unsigned int msr = (unsigned int)(key >> 32);
            unsigned int mbr = (msr & 0x80000000u) ? (msr ^ 0x80000000u) : ~msr;
            float mw   = __uint_as_float(mbr);
            int   amw  = 0x7FFFFFFF - (int)(unsigned int)(key & 0xFFFFFFFFu);
            float conf = __expf(mw) / s;       // == 1/sum(exp(x-m)) in exact math
            float acc  = (amw == lab) ? 1.0f : 0.0f;
            int b = 0;
            #pragma unroll
            for (int k = 1; k < NBINS; ++k)
                b += (conf > (float)k * (1.0f / 15.0f)) ? 1 : 0;
            atomicAdd(&sb[b],             1.0f);
            atomicAdd(&sb[NBINS + b],     conf);
            atomicAdd(&sb[2 * NBINS + b], acc);
        }

        // rotate buffers
        row = nrow;
        v0 = w0; v1 = w1; v2 = w2; v3 = w3; lab = nlab;
    }

    __syncthreads();
    if (t < 3 * NBINS)
        partials[(size_t)t * NB1 + blockIdx.x] = sb[t];
}

// Stage 2: reduce [45][NB1] partials in double, compute ece & acc.
__global__ __launch_bounds__(1024) void ece_final_kernel(
    const float* __restrict__ partials, float* __restrict__ out, int N)
{
    __shared__ double red[3 * NBINS][16];
    const int t = threadIdx.x;
    const int c = t >> 4;
    const int sub = t & 15;

    if (c < 3 * NBINS) {
        double a = 0.0;
        for (int b = sub; b < NB1; b += 16)
            a += (double)partials[(size_t)c * NB1 + b];
        red[c][sub] = a;
    }
    __syncthreads();
    if (t < 3 * NBINS) {
        double ssum = 0.0;
        #pragma unroll
        for (int i = 0; i < 16; ++i) ssum += red[t][i];
        red[t][0] = ssum;
    }
    __syncthreads();
    if (t == 0) {
        double ece = 0.0, acc = 0.0;
        const double n = (double)N;
        for (int k = 0; k < NBINS; ++k) {
            double cnt = red[k][0];
            double cs  = red[NBINS + k][0];
            double as  = red[2 * NBINS + k][0];
            if (cnt > 0.0) {
                double avg_conf = cs / cnt;
                double avg_acc  = as / cnt;
                double prop     = cnt / n;
                ece += fabs(avg_conf - avg_acc) * prop;
                acc += avg_acc * prop;
            }
        }
        out[0] = (float)(ece * 100.0);
        out[1] = (float)(acc * 100.0);
    }
}

extern "C" void kernel_launch(void* const* d_in, const int* in_sizes, int n_in,
                              void* d_out, int out_size, void* d_ws, size_t ws_size,
                              hipStream_t stream) {
    const float* logits = (const float*)d_in[0];
    const int*   labels = (const int*)d_in[1];
    float* out = (float*)d_out;

    const int N = in_sizes[1];            // 65536
    const int C = in_sizes[0] / N;        // 1000

    float* partials = (float*)d_ws;       // 45 * NB1 floats

    ece_rows_kernel<<<NB1, BLK, 0, stream>>>(logits, labels, partials, N, C);
    ece_final_kernel<<<1, 1024, 0, stream>>>(partials, out, N);
}

// Round 5
// 345.900 us; speedup vs baseline: 1.1255x; 1.1255x over previous
//
#include <hip/hip_runtime.h>
#include <hip/hip_bf16.h>
#include <math.h>

#define NBINS 15
#define NB1 1024          // stage-1 blocks
#define BLK 256           // threads per block (4 waves)

typedef float float4n __attribute__((ext_vector_type(4)));  // native vec for nontemporal builtins

// Stage 1: one wave per row, register ping-pong prefetch across rows,
// nontemporal streaming loads (read-once data), fused (sum | max/argmax-key)
// butterfly. Per-block bin sums in LDS; partials transposed [45][NB1].
__global__ __launch_bounds__(BLK, 4) void ece_rows_kernel(
    const float* __restrict__ logits,
    const int*   __restrict__ labels,
    float* __restrict__ partials,   // [3*NBINS][NB1]
    int N, int C)
{
    __shared__ float sb[3 * NBINS];
    const int t = threadIdx.x;
    if (t < 3 * NBINS) sb[t] = 0.0f;
    __syncthreads();

    const int lane   = t & 63;
    const int wave   = (blockIdx.x * BLK + t) >> 6;
    const int nwaves = (NB1 * BLK) >> 6;        // 4096 -> 16 rows per wave
    const int nvec   = (C + 3) >> 2;            // 250 for C=1000

    const int  i0 = lane, i1 = lane + 64, i2 = lane + 128, i3 = lane + 192;
    const bool q0 = i0 < nvec, q1 = i1 < nvec, q2 = i2 < nvec, q3 = i3 < nvec;
    const float4n NEG = { -INFINITY, -INFINITY, -INFINITY, -INFINITY };

    float4n v0 = NEG, v1 = NEG, v2 = NEG, v3 = NEG;
    int lab = 0;
    int row = wave;
    if (row < N) {
        const float4n* __restrict__ rp = (const float4n*)(logits + (size_t)row * C);
        if (q0) v0 = __builtin_nontemporal_load(rp + i0);
        if (q1) v1 = __builtin_nontemporal_load(rp + i1);
        if (q2) v2 = __builtin_nontemporal_load(rp + i2);
        if (q3) v3 = __builtin_nontemporal_load(rp + i3);
        lab = labels[row];
    }

    while (row < N) {
        // ---- prefetch next row (issues before current row's compute) ----
        const int nrow = row + nwaves;
        float4n w0 = NEG, w1 = NEG, w2 = NEG, w3 = NEG;
        int nlab = 0;
        if (nrow < N) {
            const float4n* __restrict__ rp = (const float4n*)(logits + (size_t)nrow * C);
            if (q0) w0 = __builtin_nontemporal_load(rp + i0);
            if (q1) w1 = __builtin_nontemporal_load(rp + i1);
            if (q2) w2 = __builtin_nontemporal_load(rp + i2);
            if (q3) w3 = __builtin_nontemporal_load(rp + i3);
            nlab = labels[nrow];
        }

        // ---- process current row ----
        const float* e0 = (const float*)&v0;
        const float* e1 = (const float*)&v1;
        const float* e2 = (const float*)&v2;
        const float* e3 = (const float*)&v3;

        float s0 = __expf(e0[0]) + __expf(e0[1]) + __expf(e0[2]) + __expf(e0[3]);
        float s1 = __expf(e1[0]) + __expf(e1[1]) + __expf(e1[2]) + __expf(e1[3]);
        float s2 = __expf(e2[0]) + __expf(e2[1]) + __expf(e2[2]) + __expf(e2[3]);
        float s3 = __expf(e3[0]) + __expf(e3[1]) + __expf(e3[2]) + __expf(e3[3]);
        float s  = (s0 + s1) + (s2 + s3);

        float m0 = fmaxf(fmaxf(e0[0], e0[1]), fmaxf(e0[2], e0[3]));
        float m1 = fmaxf(fmaxf(e1[0], e1[1]), fmaxf(e1[2], e1[3]));
        float m2 = fmaxf(fmaxf(e2[0], e2[1]), fmaxf(e2[2], e2[3]));
        float m3 = fmaxf(fmaxf(e3[0], e3[1]), fmaxf(e3[2], e3[3]));
        float m  = fmaxf(fmaxf(m0, m1), fmaxf(m2, m3));

        // argmax = smallest col with e==m (descending overwrite)
        int am = 0x7FFFFFFF;
        {
            const float* es[4] = { e0, e1, e2, e3 };
            #pragma unroll
            for (int k = 3; k >= 0; --k) {
                const int base = (lane + 64 * k) * 4;
                #pragma unroll
                for (int j = 3; j >= 0; --j)
                    am = (es[k][j] == m) ? (base + j) : am;
            }
        }

        // packed key: (sortable max | inverted index) -> u64 max == (max val, min col)
        unsigned int mb = __float_as_uint(m);
        unsigned int ms = mb ^ ((unsigned int)((int)mb >> 31) | 0x80000000u);
        unsigned long long key =
            ((unsigned long long)ms << 32) | (unsigned int)(0x7FFFFFFF - am);

        #pragma unroll
        for (int off = 32; off; off >>= 1) {
            unsigned long long k2 = __shfl_xor(key, off, 64);
            float sv              = __shfl_xor(s,   off, 64);
            s += sv;
            key = (k2 > key) ? k2 : key;
        }

        if (lane == 0) {
            unsigned int msr = (unsigned int)(key >> 32);
            unsigned int mbr = (msr & 0x80000000u) ? (msr ^ 0x80000000u) : ~msr;
            float mw   = __uint_as_float(mbr);
            int   amw  = 0x7FFFFFFF - (int)(unsigned int)(key & 0xFFFFFFFFu);
            float conf = __expf(mw) / s;       // == 1/sum(exp(x-m)) in exact math
            float acc  = (amw == lab) ? 1.0f : 0.0f;
            int b = 0;
            #pragma unroll
            for (int k = 1; k < NBINS; ++k)
                b += (conf > (float)k * (1.0f / 15.0f)) ? 1 : 0;
            atomicAdd(&sb[b],             1.0f);
            atomicAdd(&sb[NBINS + b],     conf);
            atomicAdd(&sb[2 * NBINS + b], acc);
        }

        row = nrow;
        v0 = w0; v1 = w1; v2 = w2; v3 = w3; lab = nlab;
    }

    __syncthreads();
    if (t < 3 * NBINS)
        partials[(size_t)t * NB1 + blockIdx.x] = sb[t];
}

// Stage 2: reduce [45][NB1] partials in double, compute ece & acc.
__global__ __launch_bounds__(1024) void ece_final_kernel(
    const float* __restrict__ partials, float* __restrict__ out, int N)
{
    __shared__ double red[3 * NBINS][16];
    const int t = threadIdx.x;
    const int c = t >> 4;
    const int sub = t & 15;

    if (c < 3 * NBINS) {
        double a = 0.0;
        for (int b = sub; b < NB1; b += 16)
            a += (double)partials[(size_t)c * NB1 + b];
        red[c][sub] = a;
    }
    __syncthreads();
    if (t < 3 * NBINS) {
        double ssum = 0.0;
        #pragma unroll
        for (int i = 0; i < 16; ++i) ssum += red[t][i];
        red[t][0] = ssum;
    }
    __syncthreads();
    if (t == 0) {
        double ece = 0.0, acc = 0.0;
        const double n = (double)N;
        for (int k = 0; k < NBINS; ++k) {
            double cnt = red[k][0];
            double cs  = red[NBINS + k][0];
            double as  = red[2 * NBINS + k][0];
            if (cnt > 0.0) {
                double avg_conf = cs / cnt;
                double avg_acc  = as / cnt;
                double prop     = cnt / n;
                ece += fabs(avg_conf - avg_acc) * prop;
                acc += avg_acc * prop;
            }
        }
        out[0] = (float)(ece * 100.0);
        out[1] = (float)(acc * 100.0);
    }
}

extern "C" void kernel_launch(void* const* d_in, const int* in_sizes, int n_in,
                              void* d_out, int out_size, void* d_ws, size_t ws_size,
                              hipStream_t stream) {
    const float* logits = (const float*)d_in[0];
    const int*   labels = (const int*)d_in[1];
    float* out = (float*)d_out;

    const int N = in_sizes[1];            // 65536
    const int C = in_sizes[0] / N;        // 1000

    float* partials = (float*)d_ws;       // 45 * NB1 floats

    ece_rows_kernel<<<NB1, BLK, 0, stream>>>(logits, labels, partials, N, C);
    ece_final_kernel<<<1, 1024, 0, stream>>>(partials, out, N);
}